// Round 3
// baseline (75.603 us; speedup 1.0000x reference)
//
#include <hip/hip_runtime.h>
#include <stdint.h>

// GCMConv on MI355X. Data model (verified rounds 0-3):
//   x      : float32 (1,16384,8,3,3,2)  — complex pair = v2f
//   weight : float32 (4,9,33)
//   out    : float32 (1,16384,8,3,3,2)
//
// Round-16 "register blocking: 8 threads/site, 4 M-accumulators/thread":
//   LDS model said the old 16-thread/site scheme was LDS-instruction-bound:
//   each tile read (16-lane broadcast) fed only 2 M-accumulators, so the CU
//   paid 2x the minimum ds_read issue count (~9 us/CU vs 2.9 us VALU).
//   Now thread (u,h) h=0,1 builds M[u,2h], M[u,2h+1], M[u,4+2h], M[u,5+2h]
//   AND the cc(v=8) share in ONE pass over the 16 tiles -> LDS ops halve.
//   - cc folded into main loop with pre-zeroed weights (no divergence, no
//     separate tile re-read loop)
//   - phase 1: each thread does TWO transports (tiles u*4+2h, u*4+2h+1);
//     W-channel loads are 18 contiguous v2f
//   - tile slots permuted (slot = t>>1 | (t&1)<<3) so both write batches
//     spread over all 8 LDS granule groups; site stride 166 v2f (83 lines,
//     83%8=3) puts the 8 sites of a wave on 8 distinct groups
//   - weight rows padded to 49 float4 (stride 784 B) for granule spread
//   - reduction over h only: ONE shfl_xor step
//   - wave-local fence instead of barrier (sites live in 8-lane groups)
//   Grid: 512 blocks = 2/CU (grid-limited); LDS 48.8 KB; ~140 VGPR.

typedef float v2f __attribute__((ext_vector_type(2)));

#define SPB 32            // sites per block
#define TPB 256           // 8 threads per site
#define NSITES 16384
#define TS_TILE 10        // v2f per tile slot (80 B, 16B-aligned)
#define TS2_SITE 166      // v2f per site: 16*10 + 6 pad (1328 B = 83 lines)
#define WROW 49           // float4 per (u,h) weight row: 16*3 + 1 pad

#if defined(__has_builtin)
#if __has_builtin(__builtin_elementwise_fma)
#define HAVE_EW_FMA 1
#endif
#endif

__device__ __forceinline__ v2f pkfma(v2f a, v2f b, v2f c){
#ifdef HAVE_EW_FMA
    return __builtin_elementwise_fma(a, b, c);
#else
    v2f r; r.x = fmaf(a.x, b.x, c.x); r.y = fmaf(a.y, b.y, c.y); return r;
#endif
}
__device__ __forceinline__ v2f spl(float s){ return (v2f){s, s}; }
__device__ __forceinline__ v2f pn (float s){ return (v2f){s, -s}; }
__device__ __forceinline__ v2f np (float s){ return (v2f){-s, s}; }
__device__ __forceinline__ v2f swp(v2f a){ return __builtin_shufflevector(a, a, 1, 0); }
__device__ __forceinline__ v2f zero2(){ return (v2f){0.f, 0.f}; }

__device__ __forceinline__ int neigh(int s, int a){
    // dims (8,8,16,16): d3 bits[0:4), d2 bits[4:8), d1 bits[8:11), d0 bits[11:14)
    if (a == 3) return (s & ~15)        | ((s + 1)    & 15);
    if (a == 2) return (s & ~(15 << 4)) | ((s + 16)   & (15 << 4));
    if (a == 1) return (s & ~(7 << 8))  | ((s + 256)  & (7 << 8));
    return              (s & ~(7 << 11))| ((s + 2048) & (7 << 11));
}

// tt = U * W * U^+  (3x3 complex)
__device__ __forceinline__ void transport(const v2f* uc, const v2f* wc, v2f* tt){
    v2f t1[9];
    #pragma unroll
    for (int r = 0; r < 3; r++){
        #pragma unroll
        for (int k = 0; k < 3; k++){
            v2f acc = zero2();
            #pragma unroll
            for (int j = 0; j < 3; j++){
                v2f a_ = uc[r*3+j], b_ = wc[j*3+k];
                acc = pkfma(spl(a_.x), b_, acc);
                acc = pkfma(np(a_.y), swp(b_), acc);
            }
            t1[r*3+k] = acc;
        }
    }
    #pragma unroll
    for (int r = 0; r < 3; r++){
        #pragma unroll
        for (int k = 0; k < 3; k++){
            v2f acc = zero2();
            #pragma unroll
            for (int j = 0; j < 3; j++){
                v2f a_ = t1[r*3+j], b_ = uc[k*3+j];
                acc = pkfma(pn(a_.x), b_, acc);
                acc = pkfma(spl(a_.y), swp(b_), acc);
            }
            tt[r*3+k] = acc;
        }
    }
}

__device__ __forceinline__ void store_tile(v2f* dst, const v2f* tt){
    float4* dst4 = (float4*)dst;
    dst4[0] = make_float4(tt[0].x, tt[0].y, tt[1].x, tt[1].y);
    dst4[1] = make_float4(tt[2].x, tt[2].y, tt[3].x, tt[3].y);
    dst4[2] = make_float4(tt[4].x, tt[4].y, tt[5].x, tt[5].y);
    dst4[3] = make_float4(tt[6].x, tt[6].y, tt[7].x, tt[7].y);
    dst[8] = tt[8];
}

__device__ __forceinline__ void load_tile(v2f* tc, const v2f* tp){
    const float4* tp4 = (const float4*)tp;
    float4 q0 = tp4[0], q1 = tp4[1], q2 = tp4[2], q3 = tp4[3];
    tc[0] = (v2f){q0.x, q0.y}; tc[1] = (v2f){q0.z, q0.w};
    tc[2] = (v2f){q1.x, q1.y}; tc[3] = (v2f){q1.z, q1.w};
    tc[4] = (v2f){q2.x, q2.y}; tc[5] = (v2f){q2.z, q2.w};
    tc[6] = (v2f){q3.x, q3.y}; tc[7] = (v2f){q3.z, q3.w};
    tc[8] = tp[8];
}

__global__ __launch_bounds__(TPB, 2)
void gcm_fused(const float* __restrict__ xp,
               const float* __restrict__ wgt,
               float* __restrict__ outp)
{
    __shared__ alignas(16) v2f    lt[SPB * TS2_SITE];
    __shared__ alignas(16) float4 wpk[8 * WROW];   // [(u*2+h)*49 + k*3 + {0,1,2}]
    const v2f* x2 = (const v2f*)xp;
    v2f* o2 = (v2f*)outp;

    const int tid = threadIdx.x;
    const int h   = tid & 1;
    const int u   = (tid >> 1) & 3;
    const int u2h = tid & 7;            // u*2 + h
    const int sl  = tid >> 3;           // site within block (0..31)
    const int s   = blockIdx.x * SPB + sl;
    const int g1  = 2 * h, g2 = 2 * h + 1;

    // ---- phase-1 x loads issued first (overlap staging + barrier)
    v2f uc[9], wcA[9], wcB[9];
    {
        const v2f* up = x2 + (s * 8 + u) * 9;
        #pragma unroll
        for (int e = 0; e < 9; e++) uc[e] = up[e];
    }
    {
        const int sn = neigh(s, u);
        const v2f* wp = x2 + (sn * 8 + 4 + g1) * 9;   // 18 contiguous v2f
        #pragma unroll
        for (int e = 0; e < 9; e++) wcA[e] = wp[e];
        #pragma unroll
        for (int e = 0; e < 9; e++) wcB[e] = wp[9 + e];
    }

    // ---- stage packed weights (128 entries; slot k -> logical w16)
    if (tid < 128){
        const int u_ = tid >> 5, h_ = (tid >> 4) & 1, k = tid & 15;
        const int w16 = (k < 8) ? 2 * k : 2 * k - 15;
        const float* base = wgt + u_ * 297;
        const int a1 = 2 * h_, a2 = 2 * h_ + 1;
        float4 wA = make_float4(base[a1*33 + w16],     base[a1*33 + 16 + w16],
                                base[a2*33 + w16],     base[a2*33 + 16 + w16]);
        float4 wB = make_float4(base[(4+a1)*33 + w16], base[(4+a1)*33 + 16 + w16],
                                base[(4+a2)*33 + w16], base[(4+a2)*33 + 16 + w16]);
        const bool own = ((w16 >> 3) == h_);
        float4 wC = make_float4(own ? base[264 + w16] : 0.f,
                                own ? base[280 + w16] : 0.f, 0.f, 0.f);
        float4* row = wpk + (u_ * 2 + h_) * WROW + k * 3;
        row[0] = wA; row[1] = wB; row[2] = wC;
    }
    __syncthreads();   // weight visibility (the only block-wide barrier)

    // ---- phase 1: two transports; tile t=u*4+2h+d stored at slot (t>>1)|((t&1)<<3)
    {
        v2f tt[9];
        transport(uc, wcA, tt);
        store_tile(&lt[sl * TS2_SITE + u2h * TS_TILE], tt);         // slot = u2h
        transport(uc, wcB, tt);
        store_tile(&lt[sl * TS2_SITE + (8 + u2h) * TS_TILE], tt);   // slot = 8+u2h
    }

    // pass-through copy of u channels from registers (one half of lanes)
    if (h == 1){
        v2f* dst = o2 + (s * 8 + u) * 9;
        #pragma unroll
        for (int e = 0; e < 9; e++) dst[e] = uc[e];
    }

    // ---- wave-local fence: each site's 8 threads are within one wave
    asm volatile("s_waitcnt lgkmcnt(0)" ::: "memory");
    __builtin_amdgcn_sched_barrier(0);

    // ============ phase 2 ============
    v2f M1a[9], M1b[9], M2a[9], M2b[9], cc[9];
    #pragma unroll
    for (int e = 0; e < 9; e++){
        M1a[e] = zero2(); M1b[e] = zero2();
        M2a[e] = zero2(); M2b[e] = zero2(); cc[e] = zero2();
    }

    const v2f* tbase = &lt[sl * TS2_SITE];
    const float4* wrow = wpk + u2h * WROW;

    // main loop over the 16 slots (order-free; weights staged in slot order)
    #pragma unroll 2
    for (int k = 0; k < 16; k++){
        v2f tc[9];
        load_tile(tc, tbase + k * TS_TILE);
        const float4 wA = wrow[k*3], wB = wrow[k*3 + 1];
        const float2 w8 = *(const float2*)&wrow[k*3 + 2];
        #pragma unroll
        for (int i = 0; i < 3; i++){
            #pragma unroll
            for (int j = 0; j < 3; j++){
                const int e = i*3+j, eT = j*3+i;
                M1a[e] = pkfma(spl(wA.x), tc[e],  M1a[e]);
                M1a[e] = pkfma(pn(wA.y),  tc[eT], M1a[e]);
                M1b[e] = pkfma(spl(wA.z), tc[e],  M1b[e]);
                M1b[e] = pkfma(pn(wA.w),  tc[eT], M1b[e]);
                M2a[e] = pkfma(spl(wB.x), tc[e],  M2a[e]);
                M2a[e] = pkfma(pn(wB.y),  tc[eT], M2a[e]);
                M2b[e] = pkfma(spl(wB.z), tc[e],  M2b[e]);
                M2b[e] = pkfma(pn(wB.w),  tc[eT], M2b[e]);
                cc[e]  = pkfma(spl(w8.x), tc[e],  cc[e]);
                cc[e]  = pkfma(pn(w8.y),  tc[eT], cc[e]);
            }
        }
    }

    // ---- identity (w=32) contributions to the diagonals (global, L2-hot)
    {
        const float* wub = wgt + u * 297;
        const float iA = wub[g1 * 33 + 32];
        const float iB = wub[g2 * 33 + 32];
        const float iC = wub[(4 + g1) * 33 + 32];
        const float iD = wub[(4 + g2) * 33 + 32];
        M1a[0].x += iA; M1a[4].x += iA; M1a[8].x += iA;
        M1b[0].x += iB; M1b[4].x += iB; M1b[8].x += iB;
        M2a[0].x += iC; M2a[4].x += iC; M2a[8].x += iC;
        M2b[0].x += iD; M2b[4].x += iD; M2b[8].x += iD;
        if (h == 0){
            const float i8 = wub[296];
            cc[0].x += i8; cc[4].x += i8; cc[8].x += i8;
        }
    }

    // ---- epilogue: cc += W_g1 M1a + W_g2 M1b + W_g1^+ M2a + W_g2^+ M2b
    v2f wgA[9], wgB[9];
    {
        const v2f* wp = x2 + (s * 8 + 4 + g1) * 9;   // 18 contiguous v2f
        #pragma unroll
        for (int e = 0; e < 9; e++) wgA[e] = wp[e];
        #pragma unroll
        for (int e = 0; e < 9; e++) wgB[e] = wp[9 + e];
    }
    #pragma unroll
    for (int i = 0; i < 3; i++){
        #pragma unroll
        for (int k = 0; k < 3; k++){
            v2f acc = cc[i*3+k];
            #pragma unroll
            for (int j = 0; j < 3; j++){
                v2f a_ = wgA[i*3+j], m = M1a[j*3+k];
                acc = pkfma(spl(a_.x), m,      acc);
                acc = pkfma(np(a_.y),  swp(m), acc);
            }
            #pragma unroll
            for (int j = 0; j < 3; j++){
                v2f a_ = wgB[i*3+j], m = M1b[j*3+k];
                acc = pkfma(spl(a_.x), m,      acc);
                acc = pkfma(np(a_.y),  swp(m), acc);
            }
            #pragma unroll
            for (int j = 0; j < 3; j++){
                v2f b_ = wgA[j*3+i], m = M2a[j*3+k];
                acc = pkfma(spl(b_.x), m,      acc);
                acc = pkfma(pn(b_.y),  swp(m), acc);
            }
            #pragma unroll
            for (int j = 0; j < 3; j++){
                v2f b_ = wgB[j*3+i], m = M2b[j*3+k];
                acc = pkfma(spl(b_.x), m,      acc);
                acc = pkfma(pn(b_.y),  swp(m), acc);
            }
            cc[i*3+k] = acc;
        }
    }

    // --- reduce partials over h (lane bit 0) and store
    #pragma unroll
    for (int e = 0; e < 9; e++){
        cc[e].x += __shfl_xor(cc[e].x, 1);
        cc[e].y += __shfl_xor(cc[e].y, 1);
    }
    if (h == 0){
        v2f* dst = o2 + (s * 8 + 4 + u) * 9;
        #pragma unroll
        for (int e = 0; e < 9; e++) dst[e] = cc[e];
    }
}

extern "C" void kernel_launch(void* const* d_in, const int* in_sizes, int n_in,
                              void* d_out, int out_size, void* d_ws, size_t ws_size,
                              hipStream_t stream)
{
    const float* x = (const float*)d_in[0];
    const float* w = (const float*)d_in[1];
    float* out = (float*)d_out;
    dim3 grid(NSITES / SPB);
    dim3 block(TPB);
    hipLaunchKernelGGL(gcm_fused, grid, block, 0, stream, x, w, out);
}